// Round 7
// baseline (137.369 us; speedup 1.0000x reference)
//
#include <hip/hip_runtime.h>

// GCN aggregation: out = A @ embeds, A in COO with SORTED rows.
// N=100000, E=1.6M, D=64.
//
// Structure = R0 (best-measured, 126.7us): prep (quantize + row_ptr, one
// grid-partitioned launch) then q8 gather, 16 lanes/row x 4 rows/wave.
// int8 table w/ per-row scale (6.4 MB, 64 B/row) passes absmax.
//
// Ledger: R1 issue-count NULL; R2 row-pair regress; R3 atomics regress 2x;
// R4 wave-per-row regress 1.7x; R5 extra-launch pw-pack net -13us;
// R6 bf16 table regress (2x line bytes + padding VALU, gather 49us).
//
// R7: ISOLATED pipelining on the R0 winner. Ping-pong over FULL 8-edge
// batches only (no padding conditionals): batch i+1's col/val/gather/scale
// loads are issued before batch i's compute, so the ~300-500cy L2/L3
// gather latency overlaps compute instead of serializing per batch.
// Tail = R0's 4-edge block + scalar loop, unchanged.

#define GCN_D 64

typedef float f4 __attribute__((ext_vector_type(4)));

__global__ __launch_bounds__(256) void prep_kernel(
    const float* __restrict__ embeds,
    unsigned char* __restrict__ ebq,    // N x 64 uint8 (offset-128)
    float* __restrict__ scale,          // N fp32 per-row scales
    int quant_blocks,
    const int* __restrict__ edge_row, int* __restrict__ row_ptr, int E, int N)
{
    if ((int)blockIdx.x < quant_blocks) {
        // 8 lanes per row, 8 dims (32 B) per lane.
        const int t   = blockIdx.x * blockDim.x + threadIdx.x;
        const int row = t >> 3;
        if (row >= N) return;
        const int l8 = (threadIdx.x & 7) * 8;

        const f4 a = __builtin_nontemporal_load(
            (const f4*)(embeds + (size_t)row * GCN_D + l8));
        const f4 b = __builtin_nontemporal_load(
            (const f4*)(embeds + (size_t)row * GCN_D + l8 + 4));

        float m = fmaxf(fmaxf(fmaxf(fabsf(a.x), fabsf(a.y)),
                              fmaxf(fabsf(a.z), fabsf(a.w))),
                        fmaxf(fmaxf(fabsf(b.x), fabsf(b.y)),
                              fmaxf(fabsf(b.z), fabsf(b.w))));
        m = fmaxf(m, __shfl_xor(m, 1));
        m = fmaxf(m, __shfl_xor(m, 2));
        m = fmaxf(m, __shfl_xor(m, 4));

        const float inv = (m > 0.f) ? 127.f / m : 0.f;
        const int q0 = (int)rintf(fminf(fmaxf(a.x * inv, -127.f), 127.f)) + 128;
        const int q1 = (int)rintf(fminf(fmaxf(a.y * inv, -127.f), 127.f)) + 128;
        const int q2 = (int)rintf(fminf(fmaxf(a.z * inv, -127.f), 127.f)) + 128;
        const int q3 = (int)rintf(fminf(fmaxf(a.w * inv, -127.f), 127.f)) + 128;
        const int q4 = (int)rintf(fminf(fmaxf(b.x * inv, -127.f), 127.f)) + 128;
        const int q5 = (int)rintf(fminf(fmaxf(b.y * inv, -127.f), 127.f)) + 128;
        const int q6 = (int)rintf(fminf(fmaxf(b.z * inv, -127.f), 127.f)) + 128;
        const int q7 = (int)rintf(fminf(fmaxf(b.w * inv, -127.f), 127.f)) + 128;

        unsigned int p0 =
            (unsigned)q0 | ((unsigned)q1 << 8) | ((unsigned)q2 << 16) | ((unsigned)q3 << 24);
        unsigned int p1 =
            (unsigned)q4 | ((unsigned)q5 << 8) | ((unsigned)q6 << 16) | ((unsigned)q7 << 24);

        unsigned int* dst = (unsigned int*)(ebq + (size_t)row * GCN_D + l8);
        dst[0] = p0;
        dst[1] = p1;
        if ((threadIdx.x & 7) == 0) scale[row] = m * (1.f / 127.f);
    } else {
        const int e = (blockIdx.x - quant_blocks) * blockDim.x + threadIdx.x;
        if (e >= E) return;
        const int r    = edge_row[e];
        const int prev = (e == 0) ? -1 : edge_row[e - 1];
        for (int k = prev + 1; k <= r; ++k) row_ptr[k] = e;
        if (e == E - 1)
            for (int k = r + 1; k <= N; ++k) row_ptr[k] = E;
    }
}

__device__ __forceinline__ void q8_fma4(unsigned int g, float w, f4& acc) {
    acc.x += w * (float)( g        & 0xffu);
    acc.y += w * (float)((g >> 8)  & 0xffu);
    acc.z += w * (float)((g >> 16) & 0xffu);
    acc.w += w * (float)( g >> 24);
}

__global__ __launch_bounds__(256) void gcn_row_q8_kernel(
    const int* __restrict__ row_ptr,
    const int* __restrict__ edge_col,
    const float* __restrict__ edge_val,
    const unsigned char* __restrict__ ebq,
    const float* __restrict__ scale,
    float* __restrict__ out,
    int N)
{
    const int tid = blockIdx.x * blockDim.x + threadIdx.x;
    const int row = tid >> 4;
    if (row >= N) return;
    const int db = (threadIdx.x & 15) * 4;   // dim base (4 dims/lane) = byte offset

    const int p0 = row_ptr[row];
    const int p1 = row_ptr[row + 1];

    f4    acc  = (f4)0.0f;
    float wsum = 0.0f;
    int k = p0;

    auto LOAD = [&](int kk, int* c, float* v, unsigned* g, float* s) {
        #pragma unroll
        for (int j = 0; j < 8; ++j) { c[j] = edge_col[kk + j]; v[j] = edge_val[kk + j]; }
        #pragma unroll
        for (int j = 0; j < 8; ++j) {
            g[j] = *(const unsigned*)(ebq + (size_t)c[j] * GCN_D + db);
            s[j] = scale[c[j]];
        }
    };
    auto COMP = [&](const float* v, const unsigned* g, const float* s) {
        #pragma unroll
        for (int j = 0; j < 8; ++j) {
            const float w = v[j] * s[j];
            q8_fma4(g[j], w, acc);
            wsum += w;
        }
    };

    // Ping-pong pipeline over FULL 8-edge batches: batch i+1's loads are
    // in flight during batch i's compute. No padding conditionals.
    const int nb = (p1 - p0) >> 3;
    if (nb > 0) {
        int      cA[8], cB[8];
        float    vA[8], vB[8], sA[8], sB[8];
        unsigned gA[8], gB[8];

        LOAD(k, cA, vA, gA, sA); k += 8;
        int b = 1;
        for (; b + 1 < nb; b += 2) {
            LOAD(k, cB, vB, gB, sB); k += 8;
            COMP(vA, gA, sA);
            LOAD(k, cA, vA, gA, sA); k += 8;
            COMP(vB, gB, sB);
        }
        if (b < nb) {
            LOAD(k, cB, vB, gB, sB); k += 8;
            COMP(vA, gA, sA);
            COMP(vB, gB, sB);
        } else {
            COMP(vA, gA, sA);
        }
    }

    // Tail (<8 edges): R0's 4-edge block + scalar loop.
    if (k + 3 < p1) {
        int   c[4];
        float v[4];
        #pragma unroll
        for (int j = 0; j < 4; ++j) { c[j] = edge_col[k + j]; v[j] = edge_val[k + j]; }
        unsigned int g[4];
        float        s[4];
        #pragma unroll
        for (int j = 0; j < 4; ++j) {
            g[j] = *(const unsigned int*)(ebq + (size_t)c[j] * GCN_D + db);
            s[j] = scale[c[j]];
        }
        #pragma unroll
        for (int j = 0; j < 4; ++j) {
            const float w = v[j] * s[j];
            q8_fma4(g[j], w, acc);
            wsum += w;
        }
        k += 4;
    }
    for (; k < p1; ++k) {
        const int c = edge_col[k];
        const unsigned int g = *(const unsigned int*)(ebq + (size_t)c * GCN_D + db);
        const float w = edge_val[k] * scale[c];
        q8_fma4(g, w, acc);
        wsum += w;
    }

    acc = acc - 128.0f * wsum;   // fold out the offset-128 zero point

    __builtin_nontemporal_store(acc, (f4*)(out + (size_t)row * GCN_D + db));
}

extern "C" void kernel_launch(void* const* d_in, const int* in_sizes, int n_in,
                              void* d_out, int out_size, void* d_ws, size_t ws_size,
                              hipStream_t stream) {
    const int*   edge_row = (const int*)d_in[0];
    const int*   edge_col = (const int*)d_in[1];
    const float* edge_val = (const float*)d_in[2];
    const float* embeds   = (const float*)d_in[3];
    float*       out      = (float*)d_out;

    const int E = in_sizes[0];
    const int N = out_size / GCN_D;

    // ws layout: row_ptr | scale | int8 table (256B-aligned sections)
    int* row_ptr = (int*)d_ws;
    const size_t sc_off = (((size_t)(N + 1) * 4) + 255) & ~(size_t)255;
    float* scale = (float*)((char*)d_ws + sc_off);
    const size_t q_off = ((sc_off + (size_t)N * 4) + 255) & ~(size_t)255;
    unsigned char* ebq = (unsigned char*)d_ws + q_off;

    const int quant_blocks = (N * 8 + 255) / 256;   // 8 lanes per row
    const int rp_blocks    = (E + 255) / 256;
    prep_kernel<<<quant_blocks + rp_blocks, 256, 0, stream>>>(
        embeds, ebq, scale, quant_blocks, edge_row, row_ptr, E, N);

    const int row_blocks = (N * 16 + 255) / 256;    // 16 lanes per row
    gcn_row_q8_kernel<<<row_blocks, 256, 0, stream>>>(
        row_ptr, edge_col, edge_val, ebq, scale, out, N);
}

// Round 8
// 123.618 us; speedup vs baseline: 1.1112x; 1.1112x over previous
//
#include <hip/hip_runtime.h>

// GCN aggregation: out = A @ embeds, A in COO with SORTED rows.
// N=100000, E=1.6M, D=64.
//
// Structure: prep (quantize + row_ptr, one grid-partitioned launch) then
// q8 gather, 16 lanes/row, 16 rows/block. int8 table w/ per-row scale
// (6.4 MB, 64 B/row) passes absmax (0.094 vs 0.296).
//
// Ledger: R1 issue-count NULL; R2 row-pair regress; R3 atomics regress 2x;
// R4 wave-per-row regress 1.7x; R5 extra-launch pw-pack -13us; R6 bf16
// table regress; R7 in-wave ping-pong regress (49us, +VGPR, no overlap).
//
// R8: LDS EDGE STAGING — removes the global col/val stage from the
// dependent chain. A block's 16 rows have one contiguous edge range
// (~256 edges): all 256 threads coalesce-load col/val, premultiply
// scale[col], park (col,w) int2 in 4KB LDS (block-uniform chunk loop,
// plain __syncthreads). Group loop: LDS read (broadcast, ~120cy) ->
// ONE table gather per edge (was 4 global VMEM/edge). Tail folded into
// padded 8-batches (w=0; cheap on the LDS path).

#define GCN_D 64
#define CHUNK_E 512   // LDS edge capacity per block (4 KB); loop handles overflow

typedef float f4 __attribute__((ext_vector_type(4)));

__global__ __launch_bounds__(256) void prep_kernel(
    const float* __restrict__ embeds,
    unsigned char* __restrict__ ebq,    // N x 64 uint8 (offset-128)
    float* __restrict__ scale,          // N fp32 per-row scales
    int quant_blocks,
    const int* __restrict__ edge_row, int* __restrict__ row_ptr, int E, int N)
{
    if ((int)blockIdx.x < quant_blocks) {
        // 8 lanes per row, 8 dims (32 B) per lane.
        const int t   = blockIdx.x * blockDim.x + threadIdx.x;
        const int row = t >> 3;
        if (row >= N) return;
        const int l8 = (threadIdx.x & 7) * 8;

        const f4 a = __builtin_nontemporal_load(
            (const f4*)(embeds + (size_t)row * GCN_D + l8));
        const f4 b = __builtin_nontemporal_load(
            (const f4*)(embeds + (size_t)row * GCN_D + l8 + 4));

        float m = fmaxf(fmaxf(fmaxf(fabsf(a.x), fabsf(a.y)),
                              fmaxf(fabsf(a.z), fabsf(a.w))),
                        fmaxf(fmaxf(fabsf(b.x), fabsf(b.y)),
                              fmaxf(fabsf(b.z), fabsf(b.w))));
        m = fmaxf(m, __shfl_xor(m, 1));
        m = fmaxf(m, __shfl_xor(m, 2));
        m = fmaxf(m, __shfl_xor(m, 4));

        const float inv = (m > 0.f) ? 127.f / m : 0.f;
        const int q0 = (int)rintf(fminf(fmaxf(a.x * inv, -127.f), 127.f)) + 128;
        const int q1 = (int)rintf(fminf(fmaxf(a.y * inv, -127.f), 127.f)) + 128;
        const int q2 = (int)rintf(fminf(fmaxf(a.z * inv, -127.f), 127.f)) + 128;
        const int q3 = (int)rintf(fminf(fmaxf(a.w * inv, -127.f), 127.f)) + 128;
        const int q4 = (int)rintf(fminf(fmaxf(b.x * inv, -127.f), 127.f)) + 128;
        const int q5 = (int)rintf(fminf(fmaxf(b.y * inv, -127.f), 127.f)) + 128;
        const int q6 = (int)rintf(fminf(fmaxf(b.z * inv, -127.f), 127.f)) + 128;
        const int q7 = (int)rintf(fminf(fmaxf(b.w * inv, -127.f), 127.f)) + 128;

        unsigned int p0 =
            (unsigned)q0 | ((unsigned)q1 << 8) | ((unsigned)q2 << 16) | ((unsigned)q3 << 24);
        unsigned int p1 =
            (unsigned)q4 | ((unsigned)q5 << 8) | ((unsigned)q6 << 16) | ((unsigned)q7 << 24);

        unsigned int* dst = (unsigned int*)(ebq + (size_t)row * GCN_D + l8);
        dst[0] = p0;
        dst[1] = p1;
        if ((threadIdx.x & 7) == 0) scale[row] = m * (1.f / 127.f);
    } else {
        const int e = (blockIdx.x - quant_blocks) * blockDim.x + threadIdx.x;
        if (e >= E) return;
        const int r    = edge_row[e];
        const int prev = (e == 0) ? -1 : edge_row[e - 1];
        for (int k = prev + 1; k <= r; ++k) row_ptr[k] = e;
        if (e == E - 1)
            for (int k = r + 1; k <= N; ++k) row_ptr[k] = E;
    }
}

__device__ __forceinline__ void q8_fma4(unsigned int g, float w, f4& acc) {
    acc.x += w * (float)( g        & 0xffu);
    acc.y += w * (float)((g >> 8)  & 0xffu);
    acc.z += w * (float)((g >> 16) & 0xffu);
    acc.w += w * (float)( g >> 24);
}

__global__ __launch_bounds__(256) void gcn_row_q8_lds_kernel(
    const int* __restrict__ row_ptr,
    const int* __restrict__ edge_col,
    const float* __restrict__ edge_val,
    const unsigned char* __restrict__ ebq,
    const float* __restrict__ scale,
    float* __restrict__ out,
    int N)
{
    __shared__ int2 ls[CHUNK_E];             // (col, w = val*scale[col])

    const int brow0 = blockIdx.x * 16;       // 16 rows per block
    const int row   = brow0 + (threadIdx.x >> 4);
    const int db    = (threadIdx.x & 15) * 4;   // dim base / byte offset
    const bool rv   = (row < N);

    const int p0 = rv ? row_ptr[row]     : 0;
    const int p1 = rv ? row_ptr[row + 1] : 0;

    const int rlast = (brow0 + 16 < N) ? (brow0 + 16) : N;
    const int r0 = row_ptr[brow0];
    const int r1 = row_ptr[rlast];

    f4    acc  = (f4)0.0f;
    float wsum = 0.0f;

    for (int cb = r0; cb < r1; cb += CHUNK_E) {
        const int ce = (cb + CHUNK_E < r1) ? (cb + CHUNK_E) : r1;

        __syncthreads();                     // protect LDS reuse across chunks
        // Cooperative coalesced stage: col/val stream + scale premultiply.
        for (int i = cb + (int)threadIdx.x; i < ce; i += 256) {
            const int c = edge_col[i];
            ls[i - cb] = make_int2(c, __float_as_int(edge_val[i] * scale[c]));
        }
        __syncthreads();

        // Consume this row's slice of the chunk: padded 8-edge batches,
        // one global VMEM (table gather) per edge.
        const int k0 = (p0 > cb) ? p0 : cb;
        const int ke = (p1 < ce) ? p1 : ce;
        if (ke > k0) {
            const int nb   = (ke - k0 + 7) >> 3;
            const int lmax = ce - cb - 1;
            for (int b = 0; b < nb; ++b) {
                const int kb = k0 + b * 8;
                int   c[8];
                float w[8];
                #pragma unroll
                for (int j = 0; j < 8; ++j) {
                    int idx = kb + j - cb;
                    idx = (idx > lmax) ? lmax : idx;       // in-bounds pad
                    const int2 t = ls[idx];
                    c[j] = t.x;
                    w[j] = (kb + j < ke) ? __int_as_float(t.y) : 0.0f;
                }
                unsigned g[8];
                #pragma unroll
                for (int j = 0; j < 8; ++j)
                    g[j] = *(const unsigned*)(ebq + (size_t)c[j] * GCN_D + db);
                #pragma unroll
                for (int j = 0; j < 8; ++j) {
                    q8_fma4(g[j], w[j], acc);
                    wsum += w[j];
                }
            }
        }
    }

    if (rv) {
        acc = acc - 128.0f * wsum;           // fold out offset-128 zero point
        __builtin_nontemporal_store(acc, (f4*)(out + (size_t)row * GCN_D + db));
    }
}

extern "C" void kernel_launch(void* const* d_in, const int* in_sizes, int n_in,
                              void* d_out, int out_size, void* d_ws, size_t ws_size,
                              hipStream_t stream) {
    const int*   edge_row = (const int*)d_in[0];
    const int*   edge_col = (const int*)d_in[1];
    const float* edge_val = (const float*)d_in[2];
    const float* embeds   = (const float*)d_in[3];
    float*       out      = (float*)d_out;

    const int E = in_sizes[0];
    const int N = out_size / GCN_D;

    // ws layout: row_ptr | scale | int8 table (256B-aligned sections)
    int* row_ptr = (int*)d_ws;
    const size_t sc_off = (((size_t)(N + 1) * 4) + 255) & ~(size_t)255;
    float* scale = (float*)((char*)d_ws + sc_off);
    const size_t q_off = ((sc_off + (size_t)N * 4) + 255) & ~(size_t)255;
    unsigned char* ebq = (unsigned char*)d_ws + q_off;

    const int quant_blocks = (N * 8 + 255) / 256;   // 8 lanes per row
    const int rp_blocks    = (E + 255) / 256;
    prep_kernel<<<quant_blocks + rp_blocks, 256, 0, stream>>>(
        embeds, ebq, scale, quant_blocks, edge_row, row_ptr, E, N);

    const int row_blocks = (N + 15) / 16;           // 16 rows (256 threads) per block
    gcn_row_q8_lds_kernel<<<row_blocks, 256, 0, stream>>>(
        row_ptr, edge_col, edge_val, ebq, scale, out, N);
}